// Round 1
// baseline (877.786 us; speedup 1.0000x reference)
//
#include <hip/hip_runtime.h>

// ---------------------------------------------------------------------------
// AdaptiveTemporalAttention — MI355X gfx950
// B=4, S=2048, D=512, H=8, hd=64.
// Outputs: out (B,S,D) f32 then attn (B,H,S,S) f32, concatenated in d_out.
//
// Precision scheme: all GEMMs use bf16x2 split MFMA (hi/lo; hi*hi+hi*lo+lo*hi)
// giving ~fp32 accuracy; only PV operands (p, v) are single bf16 (errors
// average under the convex combination). Softmax done without max-subtraction
// (scores bounded ~|6|, exp<=~400, safe in f32) in a 2-pass recompute scheme
// so the 537MB attn matrix is written exactly once.
//
// Workspace layout (needs 71,303,168 B = 68 MiB):
//   0         xhi   (8,388,608)  [reused later as opre_hi]
//   8388608   xlo   (8,388,608)  [reused later as opre_lo]
//   16777216  WqT_hi/lo, WkT_hi/lo, WvT_hi/lo, WoT_hi/lo (8 x 524,288)
//   20971520  qhi, qlo, khi, klo, v, vT (6 x 8,388,608)
// ---------------------------------------------------------------------------

#define S_LEN  2048
#define DM     512
#define NH     8
#define HDIM   64
#define BATCH  4
#define BHN    32     // BATCH*NH
#define BSROWS 8192   // BATCH*S_LEN

typedef __attribute__((ext_vector_type(8))) short short8v;
typedef __attribute__((ext_vector_type(8))) unsigned short ushort8v;
typedef __attribute__((ext_vector_type(4))) float f32x4;

static __device__ __forceinline__ unsigned short bf16_rne(float f){
  unsigned int u = __float_as_uint(f);
  u = (u + 0x7FFFu + ((u >> 16) & 1u)) >> 16;
  return (unsigned short)u;
}
static __device__ __forceinline__ float bf16_f32(unsigned short h){
  return __uint_as_float(((unsigned int)h) << 16);
}
static __device__ __forceinline__ f32x4 mfma16(short8v a, short8v b, f32x4 c){
  return __builtin_amdgcn_mfma_f32_16x16x32_bf16(a, b, c, 0, 0, 0);
}

// ---------------- prep: elementwise split f32 -> (hi,lo) bf16 ----------------
__global__ void k_split(const float* __restrict__ src,
                        unsigned short* __restrict__ hi,
                        unsigned short* __restrict__ lo, int n){
  for (int i = blockIdx.x*blockDim.x + threadIdx.x; i < n;
       i += gridDim.x*blockDim.x){
    float f = src[i];
    unsigned short h = bf16_rne(f);
    hi[i] = h;
    lo[i] = bf16_rne(f - bf16_f32(h));
  }
}

// ---------------- prep: transpose 512x512 W -> WT, split ----------------
__global__ void k_wsplit(const float* __restrict__ W,
                         unsigned short* __restrict__ Thi,
                         unsigned short* __restrict__ Tlo){
  int idx = blockIdx.x*blockDim.x + threadIdx.x; // (n,k) with k fastest
  int n = idx >> 9, k = idx & 511;
  float f = W[k*DM + n];
  unsigned short h = bf16_rne(f);
  Thi[idx] = h;
  Tlo[idx] = bf16_rne(f - bf16_f32(h));
}

// ---------------- split-precision GEMM: C = A@B + bias ----------------
// A as Ahi/Alo [M][K] bf16, B as BThi/BTlo [N][K] bf16 (i.e. B transposed).
// Tile 128x64, 4 waves each 64x32 (4x2 frags of 16x16, K-step 32).
// mode 0: write C split-bf16 to outHi/outLo at [b][h][s][d] (q/k)
// mode 1: write C bf16 to outHi at [b][h][s][d]             (v)
// mode 2: write C f32 to outF[row*N+col]                    (final out)
__global__ __launch_bounds__(256) void k_gemm_split(
    const unsigned short* __restrict__ Ahi, const unsigned short* __restrict__ Alo,
    const unsigned short* __restrict__ BThi, const unsigned short* __restrict__ BTlo,
    const float* __restrict__ bias,
    float* __restrict__ outF,
    unsigned short* __restrict__ outHi, unsigned short* __restrict__ outLo,
    int M, int N, int K, int mode)
{
  const int lane = threadIdx.x & 63, w = threadIdx.x >> 6;
  const int lr = lane & 15, lk = lane >> 4;
  const int rowbase = blockIdx.y*128 + (w >> 1)*64;
  const int colbase = blockIdx.x*64  + (w & 1)*32;

  f32x4 acc[4][2];
#pragma unroll
  for (int mi=0; mi<4; ++mi)
#pragma unroll
    for (int ni=0; ni<2; ++ni) acc[mi][ni] = (f32x4){0.f,0.f,0.f,0.f};

  for (int k0 = 0; k0 < K; k0 += 32){
    short8v ah[4], al[4], bh[2], bl[2];
#pragma unroll
    for (int mi=0; mi<4; ++mi){
      size_t off = (size_t)(rowbase + mi*16 + lr)*K + k0 + lk*8;
      ah[mi] = *(const short8v*)(Ahi + off);
      al[mi] = *(const short8v*)(Alo + off);
    }
#pragma unroll
    for (int ni=0; ni<2; ++ni){
      size_t off = (size_t)(colbase + ni*16 + lr)*K + k0 + lk*8;
      bh[ni] = *(const short8v*)(BThi + off);
      bl[ni] = *(const short8v*)(BTlo + off);
    }
#pragma unroll
    for (int mi=0; mi<4; ++mi)
#pragma unroll
      for (int ni=0; ni<2; ++ni){
        acc[mi][ni] = mfma16(ah[mi], bl[ni], acc[mi][ni]);
        acc[mi][ni] = mfma16(al[mi], bh[ni], acc[mi][ni]);
        acc[mi][ni] = mfma16(ah[mi], bh[ni], acc[mi][ni]);
      }
  }

#pragma unroll
  for (int mi=0; mi<4; ++mi)
#pragma unroll
    for (int ni=0; ni<2; ++ni)
#pragma unroll
      for (int r=0; r<4; ++r){
        int row = rowbase + mi*16 + lk*4 + r;   // C/D frag: row=(lane>>4)*4+r
        int col = colbase + ni*16 + lr;         //           col=lane&15
        float c = acc[mi][ni][r] + bias[col];
        if (mode == 2){
          outF[(size_t)row*N + col] = c;
        } else {
          int b = row >> 11, s = row & 2047, hh = col >> 6, d = col & 63;
          size_t off = (((size_t)(b*NH + hh))*S_LEN + s)*HDIM + d;
          unsigned short hb = bf16_rne(c);
          outHi[off] = hb;
          if (mode == 0) outLo[off] = bf16_rne(c - bf16_f32(hb));
        }
      }
}

// ---------------- v [bh][s][d] -> vT [bh][d][s] (64x64 LDS tiles) ----------------
__global__ __launch_bounds__(256) void k_transpose_v(
    const unsigned short* __restrict__ v, unsigned short* __restrict__ vT){
  __shared__ __align__(16) unsigned short tile[64][72];
  const int bh = blockIdx.y, st = blockIdx.x;
  const int r = threadIdx.x >> 2, seg = threadIdx.x & 3;
  const unsigned short* src = v + ((size_t)bh*S_LEN + st*64 + r)*HDIM + seg*16;
  *(ushort8v*)&tile[r][seg*16]     = *(const ushort8v*)(src);
  *(ushort8v*)&tile[r][seg*16 + 8] = *(const ushort8v*)(src + 8);
  __syncthreads();
  __align__(16) unsigned short tmp[16];
#pragma unroll
  for (int i=0;i<16;++i) tmp[i] = tile[seg*16 + i][r];
  unsigned short* dst = vT + ((size_t)bh*HDIM + r)*S_LEN + st*64 + seg*16;
  *(ushort8v*)(dst)     = *(const ushort8v*)&tmp[0];
  *(ushort8v*)(dst + 8) = *(const ushort8v*)&tmp[8];
}

// ---------------- fused attention ----------------
// grid (S/64, B*H); 4 waves/block, each wave owns 16 query rows.
// Pass1: rowsum of e = exp(qk*scale*decay) (split MFMA, 6 mfma / 16 j).
// Pass2: recompute, p = e/rowsum, write attn f32, stage p in LDS as bf16,
//        PV via mfma (A=p, B=vT). Epilogue writes opre split-bf16.
__global__ __launch_bounds__(256) void k_attn(
    const unsigned short* __restrict__ qhi, const unsigned short* __restrict__ qlo,
    const unsigned short* __restrict__ khi, const unsigned short* __restrict__ klo,
    const unsigned short* __restrict__ vT,
    const float* __restrict__ ts, const int* __restrict__ am,
    const float* __restrict__ dlam,
    float* __restrict__ attn,
    unsigned short* __restrict__ ohi, unsigned short* __restrict__ olo)
{
  __shared__ __align__(16) unsigned short pbuf[4][16][40]; // [wave][row][32j + pad]
  const int w = threadIdx.x >> 6, lane = threadIdx.x & 63;
  const int lr = lane & 15, lk = lane >> 4;
  const int bh = blockIdx.y, b = bh >> 3, h = bh & 7;
  const int i0 = blockIdx.x*64 + w*16;
  const float lam = log1pf(expf(dlam[h]));   // softplus
  const float scale = 0.125f;                // hd^-0.5

  // Q A-frags (rows i0..i0+15, k = hd), kept in registers for the whole kernel
  size_t qoff = ((size_t)bh*S_LEN + i0 + lr)*HDIM + lk*8;
  const short8v qh0 = *(const short8v*)(qhi + qoff);
  const short8v qh1 = *(const short8v*)(qhi + qoff + 32);
  const short8v ql0 = *(const short8v*)(qlo + qoff);
  const short8v ql1 = *(const short8v*)(qlo + qoff + 32);

  float tir[4];
#pragma unroll
  for (int r=0;r<4;++r) tir[r] = ts[b*S_LEN + i0 + lk*4 + r];
  const float* tsb = ts + b*S_LEN;
  const int*   amb = am + b*S_LEN;

  // ---- pass 1: row sums ----
  float rs[4] = {0.f,0.f,0.f,0.f};
  for (int j0 = 0; j0 < S_LEN; j0 += 16){
    size_t kb = ((size_t)bh*S_LEN + j0 + lr)*HDIM + lk*8;
    short8v kh0 = *(const short8v*)(khi + kb);
    short8v kh1 = *(const short8v*)(khi + kb + 32);
    short8v kl0 = *(const short8v*)(klo + kb);
    short8v kl1 = *(const short8v*)(klo + kb + 32);
    f32x4 sa = (f32x4){0.f,0.f,0.f,0.f};
    sa = mfma16(qh0, kl0, sa);
    sa = mfma16(ql0, kh0, sa);
    sa = mfma16(qh0, kh0, sa);
    sa = mfma16(qh1, kl1, sa);
    sa = mfma16(ql1, kh1, sa);
    sa = mfma16(qh1, kh1, sa);
    float tj = tsb[j0 + lr];
    int   mj = amb[j0 + lr];
#pragma unroll
    for (int r=0;r<4;++r){
      float sc = sa[r]*scale*__expf(-lam*fabsf(tir[r]-tj));
      float e = mj ? __expf(sc) : 0.f;
      rs[r] += e;
    }
  }
  // butterfly sum across the 16 lanes sharing a row group
#pragma unroll
  for (int r=0;r<4;++r){
    rs[r] += __shfl_xor(rs[r], 1, 64);
    rs[r] += __shfl_xor(rs[r], 2, 64);
    rs[r] += __shfl_xor(rs[r], 4, 64);
    rs[r] += __shfl_xor(rs[r], 8, 64);
  }
  float rinv[4];
#pragma unroll
  for (int r=0;r<4;++r) rinv[r] = rs[r] > 0.f ? 1.f/rs[r] : 0.f;

  float* arow[4];
#pragma unroll
  for (int r=0;r<4;++r) arow[r] = attn + ((size_t)bh*S_LEN + i0 + lk*4 + r)*S_LEN;

  // ---- pass 2: recompute, write attn, accumulate PV ----
  f32x4 oacc[4];
#pragma unroll
  for (int nt=0;nt<4;++nt) oacc[nt] = (f32x4){0.f,0.f,0.f,0.f};

  for (int j0 = 0; j0 < S_LEN; j0 += 32){
#pragma unroll
    for (int half=0; half<2; ++half){
      int jj = j0 + half*16;
      size_t kb = ((size_t)bh*S_LEN + jj + lr)*HDIM + lk*8;
      short8v kh0 = *(const short8v*)(khi + kb);
      short8v kh1 = *(const short8v*)(khi + kb + 32);
      short8v kl0 = *(const short8v*)(klo + kb);
      short8v kl1 = *(const short8v*)(klo + kb + 32);
      f32x4 sa = (f32x4){0.f,0.f,0.f,0.f};
      sa = mfma16(qh0, kl0, sa);
      sa = mfma16(ql0, kh0, sa);
      sa = mfma16(qh0, kh0, sa);
      sa = mfma16(qh1, kl1, sa);
      sa = mfma16(ql1, kh1, sa);
      sa = mfma16(qh1, kh1, sa);
      float tj = tsb[jj + lr];
      int   mj = amb[jj + lr];
#pragma unroll
      for (int r=0;r<4;++r){
        float sc = sa[r]*scale*__expf(-lam*fabsf(tir[r]-tj));
        float e = mj ? __expf(sc) : 0.f;
        float p = e * rinv[r];
        arow[r][jj + lr] = p;                         // attn output (f32)
        pbuf[w][lk*4 + r][half*16 + lr] = bf16_rne(p);
      }
    }
    // PV: A-frag = p rows (row=lane&15, k=(lane>>4)*8+e over 32 j's)
    short8v pa = *(const short8v*)&pbuf[w][lr][lk*8];
#pragma unroll
    for (int nt=0;nt<4;++nt){
      const short8v vf = *(const short8v*)(vT +
          ((size_t)bh*HDIM + nt*16 + lr)*S_LEN + j0 + lk*8);
      oacc[nt] = mfma16(pa, vf, oacc[nt]);
    }
  }

  // epilogue: opre (split bf16) at [b*S+s][h*64+d]
#pragma unroll
  for (int nt=0;nt<4;++nt)
#pragma unroll
    for (int r=0;r<4;++r){
      int row = b*S_LEN + i0 + lk*4 + r;
      int col = h*HDIM + nt*16 + lr;
      float vo = oacc[nt][r];
      unsigned short hb = bf16_rne(vo);
      ohi[(size_t)row*DM + col] = hb;
      olo[(size_t)row*DM + col] = bf16_rne(vo - bf16_f32(hb));
    }
}

// ---------------------------------------------------------------------------
extern "C" void kernel_launch(void* const* d_in, const int* in_sizes, int n_in,
                              void* d_out, int out_size, void* d_ws, size_t ws_size,
                              hipStream_t stream){
  const float* x  = (const float*)d_in[0];
  const float* ts = (const float*)d_in[1];
  const int*   am = (const int*)d_in[2];
  const float* Wq = (const float*)d_in[3];
  const float* bq = (const float*)d_in[4];
  const float* Wk = (const float*)d_in[5];
  const float* bk = (const float*)d_in[6];
  const float* Wv = (const float*)d_in[7];
  const float* bv = (const float*)d_in[8];
  const float* Wo = (const float*)d_in[9];
  const float* bo = (const float*)d_in[10];
  const float* dl = (const float*)d_in[11];

  char* ws = (char*)d_ws;
  unsigned short* xhi = (unsigned short*)(ws);               // later reused as opre_hi
  unsigned short* xlo = (unsigned short*)(ws + 8388608ull);  // later reused as opre_lo
  unsigned short* wqt_hi = (unsigned short*)(ws + 16777216ull + 0ull*524288ull);
  unsigned short* wqt_lo = (unsigned short*)(ws + 16777216ull + 1ull*524288ull);
  unsigned short* wkt_hi = (unsigned short*)(ws + 16777216ull + 2ull*524288ull);
  unsigned short* wkt_lo = (unsigned short*)(ws + 16777216ull + 3ull*524288ull);
  unsigned short* wvt_hi = (unsigned short*)(ws + 16777216ull + 4ull*524288ull);
  unsigned short* wvt_lo = (unsigned short*)(ws + 16777216ull + 5ull*524288ull);
  unsigned short* wot_hi = (unsigned short*)(ws + 16777216ull + 6ull*524288ull);
  unsigned short* wot_lo = (unsigned short*)(ws + 16777216ull + 7ull*524288ull);
  unsigned short* qhi = (unsigned short*)(ws + 20971520ull + 0ull*8388608ull);
  unsigned short* qlo = (unsigned short*)(ws + 20971520ull + 1ull*8388608ull);
  unsigned short* khi = (unsigned short*)(ws + 20971520ull + 2ull*8388608ull);
  unsigned short* klo = (unsigned short*)(ws + 20971520ull + 3ull*8388608ull);
  unsigned short* vv  = (unsigned short*)(ws + 20971520ull + 4ull*8388608ull);
  unsigned short* vt  = (unsigned short*)(ws + 20971520ull + 5ull*8388608ull);

  float* outp  = (float*)d_out;
  float* attnp = outp + (size_t)BSROWS*DM;

  k_split<<<4096, 256, 0, stream>>>(x, xhi, xlo, BSROWS*DM);
  k_wsplit<<<1024, 256, 0, stream>>>(Wq, wqt_hi, wqt_lo);
  k_wsplit<<<1024, 256, 0, stream>>>(Wk, wkt_hi, wkt_lo);
  k_wsplit<<<1024, 256, 0, stream>>>(Wv, wvt_hi, wvt_lo);
  k_wsplit<<<1024, 256, 0, stream>>>(Wo, wot_hi, wot_lo);

  dim3 pg(DM/64, BSROWS/128);
  k_gemm_split<<<pg, 256, 0, stream>>>(xhi, xlo, wqt_hi, wqt_lo, bq,
                                       nullptr, qhi, qlo, BSROWS, DM, DM, 0);
  k_gemm_split<<<pg, 256, 0, stream>>>(xhi, xlo, wkt_hi, wkt_lo, bk,
                                       nullptr, khi, klo, BSROWS, DM, DM, 0);
  k_gemm_split<<<pg, 256, 0, stream>>>(xhi, xlo, wvt_hi, wvt_lo, bv,
                                       nullptr, vv, nullptr, BSROWS, DM, DM, 1);
  k_transpose_v<<<dim3(S_LEN/64, BHN), 256, 0, stream>>>(vv, vt);
  k_attn<<<dim3(S_LEN/64, BHN), 256, 0, stream>>>(qhi, qlo, khi, klo, vt,
                                                  ts, am, dl, attnp, xhi, xlo);
  k_gemm_split<<<pg, 256, 0, stream>>>(xhi, xlo, wot_hi, wot_lo, bo,
                                       outp, nullptr, nullptr, BSROWS, DM, DM, 2);

  (void)in_sizes; (void)n_in; (void)out_size; (void)ws_size;
}

// Round 2
// 865.389 us; speedup vs baseline: 1.0143x; 1.0143x over previous
//
#include <hip/hip_runtime.h>

// ---------------------------------------------------------------------------
// AdaptiveTemporalAttention — MI355X gfx950
// B=4, S=2048, D=512, H=8, hd=64.
// Outputs: out (B,S,D) f32 then attn (B,H,S,S) f32, concatenated in d_out.
//
// Round 2: k_attn latency fix — explicit 2-deep register double-buffer on
// K-fragment loads (VGPR was 64 -> serialized chains), vT prefetch across the
// QK+epilogue block, bijective XCD swizzle for K L2-residency, exp2-native
// epilogue (log2e folded into lam/scale). GEMMs unchanged from round 1.
// ---------------------------------------------------------------------------

#define S_LEN  2048
#define DM     512
#define NH     8
#define HDIM   64
#define BATCH  4
#define BHN    32     // BATCH*NH
#define BSROWS 8192   // BATCH*S_LEN

typedef __attribute__((ext_vector_type(8))) short short8v;
typedef __attribute__((ext_vector_type(8))) unsigned short ushort8v;
typedef __attribute__((ext_vector_type(4))) float f32x4;

static __device__ __forceinline__ unsigned short bf16_rne(float f){
  unsigned int u = __float_as_uint(f);
  u = (u + 0x7FFFu + ((u >> 16) & 1u)) >> 16;
  return (unsigned short)u;
}
static __device__ __forceinline__ float bf16_f32(unsigned short h){
  return __uint_as_float(((unsigned int)h) << 16);
}
static __device__ __forceinline__ f32x4 mfma16(short8v a, short8v b, f32x4 c){
  return __builtin_amdgcn_mfma_f32_16x16x32_bf16(a, b, c, 0, 0, 0);
}

// ---------------- prep: elementwise split f32 -> (hi,lo) bf16 ----------------
__global__ void k_split(const float* __restrict__ src,
                        unsigned short* __restrict__ hi,
                        unsigned short* __restrict__ lo, int n){
  for (int i = blockIdx.x*blockDim.x + threadIdx.x; i < n;
       i += gridDim.x*blockDim.x){
    float f = src[i];
    unsigned short h = bf16_rne(f);
    hi[i] = h;
    lo[i] = bf16_rne(f - bf16_f32(h));
  }
}

// ---------------- prep: transpose 512x512 W -> WT, split ----------------
__global__ void k_wsplit(const float* __restrict__ W,
                         unsigned short* __restrict__ Thi,
                         unsigned short* __restrict__ Tlo){
  int idx = blockIdx.x*blockDim.x + threadIdx.x; // (n,k) with k fastest
  int n = idx >> 9, k = idx & 511;
  float f = W[k*DM + n];
  unsigned short h = bf16_rne(f);
  Thi[idx] = h;
  Tlo[idx] = bf16_rne(f - bf16_f32(h));
}

// ---------------- split-precision GEMM: C = A@B + bias (unchanged) ----------------
__global__ __launch_bounds__(256) void k_gemm_split(
    const unsigned short* __restrict__ Ahi, const unsigned short* __restrict__ Alo,
    const unsigned short* __restrict__ BThi, const unsigned short* __restrict__ BTlo,
    const float* __restrict__ bias,
    float* __restrict__ outF,
    unsigned short* __restrict__ outHi, unsigned short* __restrict__ outLo,
    int M, int N, int K, int mode)
{
  const int lane = threadIdx.x & 63, w = threadIdx.x >> 6;
  const int lr = lane & 15, lk = lane >> 4;
  const int rowbase = blockIdx.y*128 + (w >> 1)*64;
  const int colbase = blockIdx.x*64  + (w & 1)*32;

  f32x4 acc[4][2];
#pragma unroll
  for (int mi=0; mi<4; ++mi)
#pragma unroll
    for (int ni=0; ni<2; ++ni) acc[mi][ni] = (f32x4){0.f,0.f,0.f,0.f};

  for (int k0 = 0; k0 < K; k0 += 32){
    short8v ah[4], al[4], bh[2], bl[2];
#pragma unroll
    for (int mi=0; mi<4; ++mi){
      size_t off = (size_t)(rowbase + mi*16 + lr)*K + k0 + lk*8;
      ah[mi] = *(const short8v*)(Ahi + off);
      al[mi] = *(const short8v*)(Alo + off);
    }
#pragma unroll
    for (int ni=0; ni<2; ++ni){
      size_t off = (size_t)(colbase + ni*16 + lr)*K + k0 + lk*8;
      bh[ni] = *(const short8v*)(BThi + off);
      bl[ni] = *(const short8v*)(BTlo + off);
    }
#pragma unroll
    for (int mi=0; mi<4; ++mi)
#pragma unroll
      for (int ni=0; ni<2; ++ni){
        acc[mi][ni] = mfma16(ah[mi], bl[ni], acc[mi][ni]);
        acc[mi][ni] = mfma16(al[mi], bh[ni], acc[mi][ni]);
        acc[mi][ni] = mfma16(ah[mi], bh[ni], acc[mi][ni]);
      }
  }

#pragma unroll
  for (int mi=0; mi<4; ++mi)
#pragma unroll
    for (int ni=0; ni<2; ++ni)
#pragma unroll
      for (int r=0; r<4; ++r){
        int row = rowbase + mi*16 + lk*4 + r;   // C/D frag: row=(lane>>4)*4+r
        int col = colbase + ni*16 + lr;         //           col=lane&15
        float c = acc[mi][ni][r] + bias[col];
        if (mode == 2){
          outF[(size_t)row*N + col] = c;
        } else {
          int b = row >> 11, s = row & 2047, hh = col >> 6, d = col & 63;
          size_t off = (((size_t)(b*NH + hh))*S_LEN + s)*HDIM + d;
          unsigned short hb = bf16_rne(c);
          outHi[off] = hb;
          if (mode == 0) outLo[off] = bf16_rne(c - bf16_f32(hb));
        }
      }
}

// ---------------- v [bh][s][d] -> vT [bh][d][s] (unchanged) ----------------
__global__ __launch_bounds__(256) void k_transpose_v(
    const unsigned short* __restrict__ v, unsigned short* __restrict__ vT){
  __shared__ __align__(16) unsigned short tile[64][72];
  const int bh = blockIdx.y, st = blockIdx.x;
  const int r = threadIdx.x >> 2, seg = threadIdx.x & 3;
  const unsigned short* src = v + ((size_t)bh*S_LEN + st*64 + r)*HDIM + seg*16;
  *(ushort8v*)&tile[r][seg*16]     = *(const ushort8v*)(src);
  *(ushort8v*)&tile[r][seg*16 + 8] = *(const ushort8v*)(src + 8);
  __syncthreads();
  __align__(16) unsigned short tmp[16];
#pragma unroll
  for (int i=0;i<16;++i) tmp[i] = tile[seg*16 + i][r];
  unsigned short* dst = vT + ((size_t)bh*HDIM + r)*S_LEN + st*64 + seg*16;
  *(ushort8v*)(dst)     = *(const ushort8v*)&tmp[0];
  *(ushort8v*)(dst + 8) = *(const ushort8v*)&tmp[8];
}

// ---------------- fused attention (round-2 rewrite) ----------------
// 1-D grid of 1024 blocks, XCD-swizzled so 32 blocks of one bh share an XCD.
// 4 waves/block, each wave owns 16 query rows. 2-deep register double-buffer
// on K-frag loads; vT frags prefetched across the QK+epilogue block.

#define LOADK(BUF, JT) { \
  size_t kb_ = (size_t)((JT)*16 + lr)*HDIM + lk*8; \
  BUF##0 = *(const short8v*)(kbhi + kb_); \
  BUF##1 = *(const short8v*)(kbhi + kb_ + 32); \
  BUF##2 = *(const short8v*)(kblo + kb_); \
  BUF##3 = *(const short8v*)(kblo + kb_ + 32); }

#define QK6(SA, KH0, KH1, KL0, KL1) { \
  SA = mfma16(qh0, KL0, SA); \
  SA = mfma16(ql0, KH0, SA); \
  SA = mfma16(qh0, KH0, SA); \
  SA = mfma16(qh1, KL1, SA); \
  SA = mfma16(ql1, KH1, SA); \
  SA = mfma16(qh1, KH1, SA); }

#define EPI1(SA, JT) { \
  float tj = tsb[(JT)*16 + lr]; \
  int mjv = amb[(JT)*16 + lr]; \
  _Pragma("unroll") \
  for (int r=0;r<4;++r){ \
    float dec = __builtin_amdgcn_exp2f(nlam2 * fabsf(tir[r]-tj)); \
    float e = __builtin_amdgcn_exp2f(SA[r]*scale2*dec); \
    rs[r] += mjv ? e : 0.f; } }

#define EPI2(SA, JT) { \
  float tj = tsb[(JT)*16 + lr]; \
  int mjv = amb[(JT)*16 + lr]; \
  _Pragma("unroll") \
  for (int r=0;r<4;++r){ \
    float dec = __builtin_amdgcn_exp2f(nlam2 * fabsf(tir[r]-tj)); \
    float e = __builtin_amdgcn_exp2f(SA[r]*scale2*dec); \
    float p = (mjv ? e : 0.f) * rinv[r]; \
    arow[r][(JT)*16 + lr] = p; \
    pbuf[w][lk*4+r][((JT)&1)*16+lr] = bf16_rne(p); } }

__global__ __launch_bounds__(256) void k_attn(
    const unsigned short* __restrict__ qhi, const unsigned short* __restrict__ qlo,
    const unsigned short* __restrict__ khi, const unsigned short* __restrict__ klo,
    const unsigned short* __restrict__ vT,
    const float* __restrict__ ts, const int* __restrict__ am,
    const float* __restrict__ dlam,
    float* __restrict__ attn,
    unsigned short* __restrict__ ohi, unsigned short* __restrict__ olo)
{
  __shared__ __align__(16) unsigned short pbuf[4][16][40]; // [wave][row][32j + pad]
  const int w = threadIdx.x >> 6, lane = threadIdx.x & 63;
  const int lr = lane & 15, lk = lane >> 4;

  // bijective XCD swizzle: 1024 blocks, 8 XCDs, 128 blocks/XCD chunk.
  // XCD x gets bh 4x..4x+3 -> K/vT slices stay L2-resident per XCD.
  const int wg = blockIdx.x;
  const int sw = (wg & 7)*128 + (wg >> 3);
  const int bh = sw >> 5;          // 0..31
  const int it = sw & 31;          // i-tile 0..31
  const int b = bh >> 3, h = bh & 7;
  const int i0 = it*64 + w*16;

  const float lam = log1pf(expf(dlam[h]));     // softplus
  const float nlam2 = -lam * 1.44269504f;      // -lam * log2(e)
  const float scale2 = 0.125f * 1.44269504f;   // hd^-0.5 * log2(e)

  // Q A-frags (rows i0..i0+15), persistent in registers
  size_t qoff = ((size_t)bh*S_LEN + i0 + lr)*HDIM + lk*8;
  const short8v qh0 = *(const short8v*)(qhi + qoff);
  const short8v qh1 = *(const short8v*)(qhi + qoff + 32);
  const short8v ql0 = *(const short8v*)(qlo + qoff);
  const short8v ql1 = *(const short8v*)(qlo + qoff + 32);

  float tir[4];
#pragma unroll
  for (int r=0;r<4;++r) tir[r] = ts[b*S_LEN + i0 + lk*4 + r];
  const float* tsb = ts + b*S_LEN;
  const int*   amb = am + b*S_LEN;
  const unsigned short* kbhi = khi + (size_t)bh*S_LEN*HDIM;
  const unsigned short* kblo = klo + (size_t)bh*S_LEN*HDIM;
  const unsigned short* vtb  = vT  + (size_t)bh*HDIM*S_LEN + (size_t)lr*S_LEN;

  short8v b0_0,b0_1,b0_2,b0_3, b1_0,b1_1,b1_2,b1_3;

  // ---- pass 1: row sums (software-pipelined, 2 sub-tiles in flight) ----
  float rs[4] = {0.f,0.f,0.f,0.f};
  LOADK(b0_, 0);
  for (int jt = 0; jt < 128; jt += 2){
    LOADK(b1_, jt+1);
    { f32x4 sa = (f32x4){0.f,0.f,0.f,0.f}; QK6(sa, b0_0,b0_1,b0_2,b0_3); EPI1(sa, jt); }
    if (jt+2 < 128) LOADK(b0_, jt+2);
    { f32x4 sa = (f32x4){0.f,0.f,0.f,0.f}; QK6(sa, b1_0,b1_1,b1_2,b1_3); EPI1(sa, jt+1); }
  }
  // butterfly sum across the 16 lanes sharing a row group
#pragma unroll
  for (int r=0;r<4;++r){
    rs[r] += __shfl_xor(rs[r], 1, 64);
    rs[r] += __shfl_xor(rs[r], 2, 64);
    rs[r] += __shfl_xor(rs[r], 4, 64);
    rs[r] += __shfl_xor(rs[r], 8, 64);
  }
  float rinv[4];
#pragma unroll
  for (int r=0;r<4;++r) rinv[r] = rs[r] > 0.f ? 1.f/rs[r] : 0.f;

  float* arow[4];
#pragma unroll
  for (int r=0;r<4;++r) arow[r] = attn + ((size_t)bh*S_LEN + i0 + lk*4 + r)*S_LEN;

  // ---- pass 2: recompute, write attn, accumulate PV ----
  f32x4 oacc0 = (f32x4){0.f,0.f,0.f,0.f};
  f32x4 oacc1 = (f32x4){0.f,0.f,0.f,0.f};
  f32x4 oacc2 = (f32x4){0.f,0.f,0.f,0.f};
  f32x4 oacc3 = (f32x4){0.f,0.f,0.f,0.f};

  LOADK(b0_, 0);
  for (int jt = 0; jt < 128; jt += 2){
    LOADK(b1_, jt+1);
    // prefetch vT frags for this 32-j block (ready by the PV below)
    size_t vo = (size_t)jt*16 + lk*8;
    short8v vf0 = *(const short8v*)(vtb + vo);
    short8v vf1 = *(const short8v*)(vtb + vo + (size_t)16*S_LEN);
    short8v vf2 = *(const short8v*)(vtb + vo + (size_t)32*S_LEN);
    short8v vf3 = *(const short8v*)(vtb + vo + (size_t)48*S_LEN);
    { f32x4 sa = (f32x4){0.f,0.f,0.f,0.f}; QK6(sa, b0_0,b0_1,b0_2,b0_3); EPI2(sa, jt); }
    if (jt+2 < 128) LOADK(b0_, jt+2);
    { f32x4 sa = (f32x4){0.f,0.f,0.f,0.f}; QK6(sa, b1_0,b1_1,b1_2,b1_3); EPI2(sa, jt+1); }
    // PV: A-frag = p rows (row=lane&15, k=(lane>>4)*8+e over 32 j's)
    short8v pa = *(const short8v*)&pbuf[w][lr][lk*8];
    oacc0 = mfma16(pa, vf0, oacc0);
    oacc1 = mfma16(pa, vf1, oacc1);
    oacc2 = mfma16(pa, vf2, oacc2);
    oacc3 = mfma16(pa, vf3, oacc3);
  }

  // epilogue: opre (split bf16) at [b*S+s][h*64+d]
  float oa[4][4] = {
    {oacc0[0],oacc0[1],oacc0[2],oacc0[3]},
    {oacc1[0],oacc1[1],oacc1[2],oacc1[3]},
    {oacc2[0],oacc2[1],oacc2[2],oacc2[3]},
    {oacc3[0],oacc3[1],oacc3[2],oacc3[3]}};
#pragma unroll
  for (int nt=0;nt<4;++nt)
#pragma unroll
    for (int r=0;r<4;++r){
      int row = b*S_LEN + i0 + lk*4 + r;
      int col = h*HDIM + nt*16 + lr;
      float vv = oa[nt][r];
      unsigned short hb = bf16_rne(vv);
      ohi[(size_t)row*DM + col] = hb;
      olo[(size_t)row*DM + col] = bf16_rne(vv - bf16_f32(hb));
    }
}

// ---------------------------------------------------------------------------
extern "C" void kernel_launch(void* const* d_in, const int* in_sizes, int n_in,
                              void* d_out, int out_size, void* d_ws, size_t ws_size,
                              hipStream_t stream){
  const float* x  = (const float*)d_in[0];
  const float* ts = (const float*)d_in[1];
  const int*   am = (const int*)d_in[2];
  const float* Wq = (const float*)d_in[3];
  const float* bq = (const float*)d_in[4];
  const float* Wk = (const float*)d_in[5];
  const float* bk = (const float*)d_in[6];
  const float* Wv = (const float*)d_in[7];
  const float* bv = (const float*)d_in[8];
  const float* Wo = (const float*)d_in[9];
  const float* bo = (const float*)d_in[10];
  const float* dl = (const float*)d_in[11];

  char* ws = (char*)d_ws;
  unsigned short* xhi = (unsigned short*)(ws);               // later reused as opre_hi
  unsigned short* xlo = (unsigned short*)(ws + 8388608ull);  // later reused as opre_lo
  unsigned short* wqt_hi = (unsigned short*)(ws + 16777216ull + 0ull*524288ull);
  unsigned short* wqt_lo = (unsigned short*)(ws + 16777216ull + 1ull*524288ull);
  unsigned short* wkt_hi = (unsigned short*)(ws + 16777216ull + 2ull*524288ull);
  unsigned short* wkt_lo = (unsigned short*)(ws + 16777216ull + 3ull*524288ull);
  unsigned short* wvt_hi = (unsigned short*)(ws + 16777216ull + 4ull*524288ull);
  unsigned short* wvt_lo = (unsigned short*)(ws + 16777216ull + 5ull*524288ull);
  unsigned short* wot_hi = (unsigned short*)(ws + 16777216ull + 6ull*524288ull);
  unsigned short* wot_lo = (unsigned short*)(ws + 16777216ull + 7ull*524288ull);
  unsigned short* qhi = (unsigned short*)(ws + 20971520ull + 0ull*8388608ull);
  unsigned short* qlo = (unsigned short*)(ws + 20971520ull + 1ull*8388608ull);
  unsigned short* khi = (unsigned short*)(ws + 20971520ull + 2ull*8388608ull);
  unsigned short* klo = (unsigned short*)(ws + 20971520ull + 3ull*8388608ull);
  unsigned short* vv  = (unsigned short*)(ws + 20971520ull + 4ull*8388608ull);
  unsigned short* vt  = (unsigned short*)(ws + 20971520ull + 5ull*8388608ull);

  float* outp  = (float*)d_out;
  float* attnp = outp + (size_t)BSROWS*DM;

  k_split<<<4096, 256, 0, stream>>>(x, xhi, xlo, BSROWS*DM);
  k_wsplit<<<1024, 256, 0, stream>>>(Wq, wqt_hi, wqt_lo);
  k_wsplit<<<1024, 256, 0, stream>>>(Wk, wkt_hi, wkt_lo);
  k_wsplit<<<1024, 256, 0, stream>>>(Wv, wvt_hi, wvt_lo);
  k_wsplit<<<1024, 256, 0, stream>>>(Wo, wot_hi, wot_lo);

  dim3 pg(DM/64, BSROWS/128);
  k_gemm_split<<<pg, 256, 0, stream>>>(xhi, xlo, wqt_hi, wqt_lo, bq,
                                       nullptr, qhi, qlo, BSROWS, DM, DM, 0);
  k_gemm_split<<<pg, 256, 0, stream>>>(xhi, xlo, wkt_hi, wkt_lo, bk,
                                       nullptr, khi, klo, BSROWS, DM, DM, 0);
  k_gemm_split<<<pg, 256, 0, stream>>>(xhi, xlo, wvt_hi, wvt_lo, bv,
                                       nullptr, vv, nullptr, BSROWS, DM, DM, 1);
  k_transpose_v<<<dim3(S_LEN/64, BHN), 256, 0, stream>>>(vv, vt);
  k_attn<<<1024, 256, 0, stream>>>(qhi, qlo, khi, klo, vt,
                                   ts, am, dl, attnp, xhi, xlo);
  k_gemm_split<<<pg, 256, 0, stream>>>(xhi, xlo, wot_hi, wot_lo, bo,
                                       outp, nullptr, nullptr, BSROWS, DM, DM, 2);

  (void)in_sizes; (void)n_in; (void)out_size; (void)ws_size;
}